// Round 3
// baseline (3553.794 us; speedup 1.0000x reference)
//
#include <hip/hip_runtime.h>

#define BB 256
#define TT 2048
#define SS 32
#define NN 19
#define NCLASS 10
#define NUNFOLD 6
#define EPSV 1e-8f
#define LOG2E 1.4426950408889634f

// ---------------------------------------------------------------------------
// Phase 1: sensory synapse precompute (input-only dependence, fully parallel).
// thread = (t, b, j).  Pairwise-merged reciprocals: two sigmoids share one rcp.
// ---------------------------------------------------------------------------
__global__ void ltc_sens_kernel(const float* __restrict__ x,
                                const float* __restrict__ iw,
                                const float* __restrict__ ib,
                                const float* __restrict__ smu,
                                const float* __restrict__ ssig,
                                const float* __restrict__ sw,
                                const float* __restrict__ serev,
                                const int* __restrict__ smask,
                                float* __restrict__ sens,
                                int t0, int tc)
{
    int gid = blockIdx.x * blockDim.x + threadIdx.x;
    int total = tc * BB * NN;
    if (gid >= total) return;
    int j  = gid % NN;
    int tb = gid / NN;
    int b  = tb % BB;
    int tl = tb / BB;
    int t  = t0 + tl;

    const float* xr = x + ((long)b * TT + t) * SS;
    float xin[SS];
    const float4* xr4 = (const float4*)xr;
#pragma unroll
    for (int q = 0; q < SS / 4; q++) {
        float4 v4 = xr4[q];
        xin[4 * q + 0] = v4.x; xin[4 * q + 1] = v4.y;
        xin[4 * q + 2] = v4.z; xin[4 * q + 3] = v4.w;
    }

    // e_s = exp2(log2e*sigma*(mu - inp)); sig = 1/(1+e)
    float ev[SS], A[SS], W[SS];
#pragma unroll
    for (int s = 0; s < SS; s++) {
        float inp = fmaf(xin[s], iw[s], ib[s]);
        int idx = s * NN + j;
        float sg = ssig[idx];
        ev[s] = __builtin_amdgcn_exp2f(fmaf(-LOG2E * sg, inp, LOG2E * sg * smu[idx]));
        float wm = sw[idx] * (float)smask[idx];
        W[s] = wm;
        A[s] = wm * serev[idx];
    }
    float num = 0.f, den = 0.f;
#pragma unroll
    for (int p = 0; p < SS / 2; p++) {
        float t0v = 1.0f + ev[2 * p];
        float t1v = 1.0f + ev[2 * p + 1];
        float rD  = __builtin_amdgcn_rcpf(t0v * t1v);
        float npn = fmaf(A[2 * p], t1v, A[2 * p + 1] * t0v);
        float npd = fmaf(W[2 * p], t1v, W[2 * p + 1] * t0v);
        num = fmaf(npn, rD, num);
        den = fmaf(npd, rD, den);
    }
    float* o = sens + ((long)tl * BB + b) * (2 * NN);
    o[j]      = num;
    o[NN + j] = den;
}

// ---------------------------------------------------------------------------
// DPP helper: lane l <- lane l+N within a 16-lane row (row_shl:N).
// ---------------------------------------------------------------------------
template <int CTRL>
__device__ __forceinline__ float dpp_shl(float x)
{
    return __int_as_float(__builtin_amdgcn_update_dpp(
        0, __float_as_int(x), CTRL, 0xf, 0xf, true));
}

__device__ __forceinline__ float rl(float v, int l)
{
    return __int_as_float(__builtin_amdgcn_readlane(__float_as_int(v), l));
}

// ---------------------------------------------------------------------------
// Phase 2: sequential scan.  One wave per batch element.
// Lane layout: lane = 16*(j/5) + 3*(j%5) + r, r=0..2 (lane 15 of each row pad).
// r==0 covers pre-neurons [0,7), r==1 [7,13), r==2 [13,19).
// Per unfold: readlane broadcast (k-major, eager exp issue), pairwise-merged
// reciprocals (7 exp + 4 rcp instead of 7+7), DPP 3-lane reduce.
// ---------------------------------------------------------------------------
__global__ void __launch_bounds__(64, 1)
ltc_scan_kernel(const float* __restrict__ mu,  const float* __restrict__ sigma,
                const float* __restrict__ w,   const float* __restrict__ erev,
                const int* __restrict__ mask,
                const float* __restrict__ gleak, const float* __restrict__ vleak,
                const float* __restrict__ cm,
                const float* __restrict__ ow,  const float* __restrict__ ob,
                const float* __restrict__ sens, float* __restrict__ outbuf,
                float* __restrict__ vstate, int t0, int tc, int initv)
{
    int b    = blockIdx.x;
    int lane = threadIdx.x;
    int row  = lane >> 4;
    int pos  = lane & 15;
    int jq   = pos / 3;                 // 0..5 (5 => pad lane)
    int r    = pos - 3 * jq;
    int j    = row * 5 + jq;
    bool pad = (jq >= 5) || (j >= NN);
    int jc   = pad ? 0 : j;

    int i0  = (r == 0) ? 0 : (r == 1) ? 7 : 13;
    int cnt = pad ? 0 : ((r == 0) ? 7 : 6);

    // folded per-lane synapse constants
    float sg2[7], sb2[7], Aa[7], Wm[7];
#pragma unroll
    for (int k = 0; k < 7; k++) {
        bool ok = (k < cnt);
        int ii = ok ? (i0 + k) : 0;
        int idx = ii * NN + jc;
        float sg = sigma[idx];
        float wmm = ok ? (w[idx] * (float)mask[idx]) : 0.f;
        sg2[k] = -LOG2E * sg;
        sb2[k] = LOG2E * sg * mu[idx];
        Aa[k]  = wmm * erev[idx];
        Wm[k]  = wmm;
    }
    float cmt   = cm[jc] * (float)NUNFOLD;
    float gl    = gleak[jc];
    float glvl  = gl * vleak[jc];
    float cgl   = cmt + gl + EPSV;
    float ow0 = ow[0], ob0 = ob[0];

    bool is_r0 = (r == 0);
    bool is_r1 = (r == 1);

    float v = initv ? 0.f : vstate[b * NN + jc];

    const float* sp0 = sens + (long)b * (2 * NN);
    float sn = sp0[jc];
    float sd = sp0[NN + jc];

    for (int t = 0; t < tc; t++) {
        float sn_nx = sn, sd_nx = sd;
        if (t + 1 < tc) {
            const float* spn = sens + ((long)(t + 1) * BB + b) * (2 * NN);
            sn_nx = spn[jc];
            sd_nx = spn[NN + jc];
        }
        float nbase = glvl + sn;
        float dbase = cgl + sd;

#pragma unroll
        for (int u = 0; u < NUNFOLD; u++) {
            float numer = fmaf(cmt, v, nbase);

            // phase 1: k-major broadcast + eager exp issue (keeps trans pipe hot)
            float ev[7];
#pragma unroll
            for (int k = 0; k < 7; k++) {
                float vi;
                if (k < 6) {
                    const int La = ((k)      / 5) * 16 + ((k)      % 5) * 3;
                    const int Lb = ((7 + k)  / 5) * 16 + ((7 + k)  % 5) * 3;
                    const int Lc = ((13 + k) / 5) * 16 + ((13 + k) % 5) * 3;
                    float a = rl(v, La);
                    float bb = rl(v, Lb);
                    float c = rl(v, Lc);
                    vi = is_r0 ? a : (is_r1 ? bb : c);
                } else {
                    const int L6 = (6 / 5) * 16 + (6 % 5) * 3;
                    vi = rl(v, L6);           // only r==0 consumes k==6
                }
                ev[k] = __builtin_amdgcn_exp2f(fmaf(sg2[k], vi, sb2[k]));
            }

            // phase 2: pairwise-merged reciprocals
            float pn = 0.f, pd = 0.f;
#pragma unroll
            for (int p = 0; p < 3; p++) {
                float t0v = 1.0f + ev[2 * p];
                float t1v = 1.0f + ev[2 * p + 1];
                float rD  = __builtin_amdgcn_rcpf(t0v * t1v);
                float npn = fmaf(Aa[2 * p], t1v, Aa[2 * p + 1] * t0v);
                float npd = fmaf(Wm[2 * p], t1v, Wm[2 * p + 1] * t0v);
                pn = fmaf(npn, rD, pn);
                pd = fmaf(npd, rD, pd);
            }
            {
                float s6 = __builtin_amdgcn_rcpf(1.0f + ev[6]);
                pn = fmaf(Aa[6], s6, pn);
                pd = fmaf(Wm[6], s6, pd);
            }

            // phase 3: 3-lane DPP reduce (base lane of each triple gets sum)
            pn = pn + dpp_shl<0x101>(pn) + dpp_shl<0x102>(pn);
            pd = pd + dpp_shl<0x101>(pd) + dpp_shl<0x102>(pd);

            // all lanes update v; only base lanes are ever read back
            v = (numer + pn) * __builtin_amdgcn_rcpf(dbase + pd);
        }
        if (lane == 0) outbuf[(long)b * TT + (t0 + t)] = fmaf(v, ow0, ob0);
        sn = sn_nx; sd = sd_nx;
    }
    if (!pad && r == 0) vstate[b * NN + j] = v;
}

// ---------------------------------------------------------------------------
// Phase 3: FC head.  One wave per (b, c).
// ---------------------------------------------------------------------------
__global__ void ltc_fc_kernel(const float* __restrict__ outbuf,
                              const float* __restrict__ fcw,
                              const float* __restrict__ fcb,
                              float* __restrict__ out)
{
    int bc = blockIdx.x;
    int b = bc / NCLASS;
    int c = bc % NCLASS;
    const float* xr = outbuf + (long)b * TT;
    const float* wr = fcw + (long)c * TT;
    float acc = 0.f;
    for (int t = threadIdx.x; t < TT; t += 64)
        acc = fmaf(xr[t], wr[t], acc);
#pragma unroll
    for (int off = 32; off > 0; off >>= 1)
        acc += __shfl_down(acc, off, 64);
    if (threadIdx.x == 0) out[bc] = acc + fcb[c];
}

// ---------------------------------------------------------------------------
extern "C" void kernel_launch(void* const* d_in, const int* in_sizes, int n_in,
                              void* d_out, int out_size, void* d_ws, size_t ws_size,
                              hipStream_t stream)
{
    const float* x     = (const float*)d_in[0];
    const float* iw    = (const float*)d_in[1];
    const float* ib    = (const float*)d_in[2];
    const float* smu   = (const float*)d_in[3];
    const float* ssig  = (const float*)d_in[4];
    const float* sw    = (const float*)d_in[5];
    const float* serev = (const float*)d_in[6];
    const float* mu    = (const float*)d_in[7];
    const float* sigma = (const float*)d_in[8];
    const float* w     = (const float*)d_in[9];
    const float* erev  = (const float*)d_in[10];
    const float* gleak = (const float*)d_in[11];
    const float* vleak = (const float*)d_in[12];
    const float* cm    = (const float*)d_in[13];
    const float* ow    = (const float*)d_in[14];
    const float* ob    = (const float*)d_in[15];
    const float* fcw   = (const float*)d_in[16];
    const float* fcb   = (const float*)d_in[17];
    const int* smask   = (const int*)d_in[18];
    const int* mask    = (const int*)d_in[19];
    float* out = (float*)d_out;

    // ws layout: [outbuf: B*T f32][vstate: B*N f32][sens: Tc*B*2N f32]
    float* outbuf = (float*)d_ws;
    float* vstate = outbuf + (long)BB * TT;
    float* sens   = vstate + (long)BB * NN;

    size_t fixed = ((size_t)BB * TT + (size_t)BB * NN) * sizeof(float);
    long avail = (long)ws_size - (long)fixed;
    long per_step = (long)BB * 2 * NN * sizeof(float);
    int Tc = (int)(avail / per_step);
    if (Tc > TT) Tc = TT;
    if (Tc < 1)  Tc = 1;

    for (int t0 = 0; t0 < TT; t0 += Tc) {
        int tc = (TT - t0 < Tc) ? (TT - t0) : Tc;
        int total = tc * BB * NN;
        int blocks = (total + 255) / 256;
        ltc_sens_kernel<<<blocks, 256, 0, stream>>>(x, iw, ib, smu, ssig, sw,
                                                    serev, smask, sens, t0, tc);
        ltc_scan_kernel<<<BB, 64, 0, stream>>>(mu, sigma, w, erev, mask, gleak,
                                               vleak, cm, ow, ob, sens, outbuf,
                                               vstate, t0, tc, t0 == 0 ? 1 : 0);
    }
    ltc_fc_kernel<<<BB * NCLASS, 64, 0, stream>>>(outbuf, fcw, fcb, out);
}